// Round 4
// baseline (196.683 us; speedup 1.0000x reference)
//
#include <hip/hip_runtime.h>
#include <hip/hip_bf16.h>

#define GLOBAL_AS __attribute__((address_space(1)))
#define LDS_AS    __attribute__((address_space(3)))

typedef __bf16 bf16x8 __attribute__((ext_vector_type(8)));
typedef float  f32x4  __attribute__((ext_vector_type(4)));

constexpr int BATCH = 8192;           // M
constexpr int IN    = 1024;
constexpr int OUT   = 1024;           // N
constexpr int KDIM  = IN * 4;         // 4096 (4 "powers" per input)
constexpr int TM = 128, TN = 64, BK = 32;

// round-to-nearest-even float -> bf16 bits (inputs finite)
__device__ __forceinline__ unsigned short f2bf(float f) {
    union { float f; unsigned u; } v; v.f = f;
    unsigned r = v.u + 0x7fffu + ((v.u >> 16) & 1u);
    return (unsigned short)(r >> 16);
}
__device__ __forceinline__ unsigned pk(unsigned short a, unsigned short b) {
    return (unsigned)a | ((unsigned)b << 16);
}

// Merged prep: blocks [0,8192) build A_big; blocks [8192,9216) build B_big + be.
// A_big[b, 4i+k] = {silu(x), x, x^2, x^3} bf16.
// B_big[o, 4i+k] = {W[o,i], C[o,i,1..3]} bf16; be[o] = bias[o] + sum_i C[o,i,0].
__global__ __launch_bounds__(256) void prep(const float* __restrict__ x,
                                            const float* __restrict__ W,
                                            const float* __restrict__ C,
                                            const float* __restrict__ bias,
                                            unsigned short* __restrict__ Ab,
                                            unsigned short* __restrict__ Bb,
                                            float* __restrict__ be) {
    if (blockIdx.x < 8192) {
        int idx = blockIdx.x * 256 + threadIdx.x;      // 8192*1024/4 threads
        float4 v = reinterpret_cast<const float4*>(x)[idx];
        float e0[4] = {v.x, v.y, v.z, v.w};
        unsigned short o[16];
#pragma unroll
        for (int j = 0; j < 4; ++j) {
            float xv = e0[j];
            float s  = xv / (1.0f + __expf(-xv));
            float x2 = xv * xv;
            o[4*j+0] = f2bf(s);
            o[4*j+1] = f2bf(xv);
            o[4*j+2] = f2bf(x2);
            o[4*j+3] = f2bf(x2 * xv);
        }
        uint4 d0 = make_uint4(pk(o[0],o[1]), pk(o[2],o[3]),   pk(o[4],o[5]),   pk(o[6],o[7]));
        uint4 d1 = make_uint4(pk(o[8],o[9]), pk(o[10],o[11]), pk(o[12],o[13]), pk(o[14],o[15]));
        uint4* dst = reinterpret_cast<uint4*>(Ab) + (size_t)idx * 2;
        dst[0] = d0;
        dst[1] = d1;
    } else {
        const int o = blockIdx.x - 8192, t = threadIdx.x;
        const int i0 = t * 4;
        const float4* c4 = reinterpret_cast<const float4*>(C + ((size_t)o * IN + i0) * 4);
        float4 w4 = *reinterpret_cast<const float4*>(W + (size_t)o * IN + i0);
        float wv[4] = {w4.x, w4.y, w4.z, w4.w};
        float s = 0.f;
        unsigned d[8];
#pragma unroll
        for (int j = 0; j < 4; ++j) {
            float4 c = c4[j];
            s += c.x;                                  // x^0 term -> bias
            d[2*j]   = pk(f2bf(wv[j]), f2bf(c.y));
            d[2*j+1] = pk(f2bf(c.z),   f2bf(c.w));
        }
        uint4* dst = reinterpret_cast<uint4*>(Bb + (size_t)o * KDIM + i0 * 4);
        dst[0] = make_uint4(d[0], d[1], d[2], d[3]);
        dst[1] = make_uint4(d[4], d[5], d[6], d[7]);
#pragma unroll
        for (int off = 32; off > 0; off >>= 1) s += __shfl_down(s, off, 64);
        __shared__ float red[4];
        if ((t & 63) == 0) red[t >> 6] = s;
        __syncthreads();
        if (t == 0) be[o] = bias[o] + red[0] + red[1] + red[2] + red[3];
    }
}

// C = A_big(8192x4096) * B_big(1024x4096)^T + be.
// Tile 128x64, 4 waves of 64x32 each -> 1024 blocks, 4 blocks/CU, 16 waves/CU.
// XCD-aware remap (each XCD owns 8 bm-stripes); LDS XOR-swizzled via source
// k-group permutation (bank-conflict-free, verified R3).
__global__ __launch_bounds__(256, 4) void gemm_kan(
        const unsigned short* __restrict__ Ab,
        const unsigned short* __restrict__ Bb,
        const float* __restrict__ be,
        float* __restrict__ out) {
    __shared__ unsigned short sA[TM * BK];   // 8 KB
    __shared__ unsigned short sB[TN * BK];   // 4 KB

    const int t   = threadIdx.x;
    const int l   = blockIdx.x;              // 0..1023
    const int j   = l >> 3;                  // 0..127
    const int bm  = (l & 7) * 8 + (j & 7);   // XCD (l&7) owns bm 8x..8x+7
    const int bn  = j >> 3;                  // 0..15
    const int lane = t & 63;
    const int wave = t >> 6;
    const int wr   = wave >> 1;              // 64-row half
    const int wc   = wave & 1;               // 32-col half
    const int l15  = lane & 15;
    const int quad = lane >> 4;

    // staging: thread t fetches (row = t>>2, kgroup = (t&3)^((row>>1)&3)), dst = t*16B
    const int rowS = t >> 2;
    const int gsw  = (t & 3) ^ ((t >> 3) & 3);
    const int colS = gsw * 8;

    const unsigned short* pa0 = Ab + (size_t)(bm * TM + rowS) * KDIM + colS;
    const unsigned short* pa1 = pa0 + (size_t)64 * KDIM;
    const unsigned short* pb0 = Bb + (size_t)(bn * TN + rowS) * KDIM + colS;

    f32x4 acc[4][2];
    const f32x4 zero = {0.f, 0.f, 0.f, 0.f};
#pragma unroll
    for (int i = 0; i < 4; ++i)
#pragma unroll
        for (int jj = 0; jj < 2; ++jj) acc[i][jj] = zero;

    // read: slot c = quad ^ ((row>>1)&3); row bases are multiples of 16
    const int xq   = (quad ^ ((l15 >> 1) & 3)) * 8;
    const int aoff = (wr * 64 + l15) * BK + xq;   // + mi*16*BK
    const int boff = (wc * 32 + l15) * BK + xq;   // + ni*16*BK

    for (int k0 = 0; k0 < KDIM; k0 += BK) {
        __syncthreads();
        __builtin_amdgcn_global_load_lds((const GLOBAL_AS void*)(pa0 + k0),
                                         (LDS_AS void*)(sA + t * 8), 16, 0, 0);
        __builtin_amdgcn_global_load_lds((const GLOBAL_AS void*)(pa1 + k0),
                                         (LDS_AS void*)(sA + 2048 + t * 8), 16, 0, 0);
        __builtin_amdgcn_global_load_lds((const GLOBAL_AS void*)(pb0 + k0),
                                         (LDS_AS void*)(sB + t * 8), 16, 0, 0);
        __syncthreads();

        bf16x8 af[4], bv[2];
#pragma unroll
        for (int i = 0; i < 4; ++i)
            af[i] = *reinterpret_cast<const bf16x8*>(sA + aoff + i * 16 * BK);
#pragma unroll
        for (int i = 0; i < 2; ++i)
            bv[i] = *reinterpret_cast<const bf16x8*>(sB + boff + i * 16 * BK);

#pragma unroll
        for (int mi = 0; mi < 4; ++mi)
#pragma unroll
            for (int ni = 0; ni < 2; ++ni)
                acc[mi][ni] = __builtin_amdgcn_mfma_f32_16x16x32_bf16(
                    af[mi], bv[ni], acc[mi][ni], 0, 0, 0);
    }

    // epilogue: C/D layout col = lane&15, row = quad*4 + reg
    float bev[2];
#pragma unroll
    for (int ni = 0; ni < 2; ++ni)
        bev[ni] = be[bn * TN + wc * 32 + ni * 16 + l15];

#pragma unroll
    for (int mi = 0; mi < 4; ++mi) {
        const int grow = bm * TM + wr * 64 + mi * 16 + quad * 4;
#pragma unroll
        for (int ni = 0; ni < 2; ++ni) {
            const int gcol = bn * TN + wc * 32 + ni * 16 + l15;
            float* po = out + (size_t)grow * OUT + gcol;
#pragma unroll
            for (int r = 0; r < 4; ++r)
                po[(size_t)r * OUT] = acc[mi][ni][r] + bev[ni];
        }
    }
}

extern "C" void kernel_launch(void* const* d_in, const int* in_sizes, int n_in,
                              void* d_out, int out_size, void* d_ws, size_t ws_size,
                              hipStream_t stream) {
    const float* x    = (const float*)d_in[0];   // [8192,1024]
    const float* W    = (const float*)d_in[1];   // [1024,1024]
    const float* C    = (const float*)d_in[2];   // [1024,1024,4]
    const float* bias = (const float*)d_in[3];   // [1024]
    float* out = (float*)d_out;

    unsigned short* Ab = (unsigned short*)d_ws;                    // 64 MB
    unsigned short* Bb = Ab + (size_t)BATCH * KDIM;                // 8 MB
    float*          be = (float*)(Bb + (size_t)OUT * KDIM);        // 4 KB

    prep<<<dim3(8192 + 1024), dim3(256), 0, stream>>>(x, W, C, bias, Ab, Bb, be);

    gemm_kan<<<dim3(1024), dim3(256), 0, stream>>>(Ab, Bb, be, out);
}

// Round 5
// 175.469 us; speedup vs baseline: 1.1209x; 1.1209x over previous
//
#include <hip/hip_runtime.h>
#include <hip/hip_bf16.h>

#define GLOBAL_AS __attribute__((address_space(1)))
#define LDS_AS    __attribute__((address_space(3)))

typedef __bf16 bf16x8 __attribute__((ext_vector_type(8)));
typedef float  f32x4  __attribute__((ext_vector_type(4)));

constexpr int BATCH = 8192;           // M
constexpr int IN    = 1024;
constexpr int OUT   = 1024;           // N
constexpr int KDIM  = IN * 4;         // 4096 (4 "powers" per input)
constexpr int TM = 128, TN = 128, BK = 64;
constexpr int NKT = KDIM / BK;        // 64 K-iterations

// round-to-nearest-even float -> bf16 bits (inputs finite)
__device__ __forceinline__ unsigned short f2bf(float f) {
    union { float f; unsigned u; } v; v.f = f;
    unsigned r = v.u + 0x7fffu + ((v.u >> 16) & 1u);
    return (unsigned short)(r >> 16);
}
__device__ __forceinline__ unsigned pk(unsigned short a, unsigned short b) {
    return (unsigned)a | ((unsigned)b << 16);
}

// Merged prep: blocks [0,8192) build A_big; blocks [8192,9216) build B_big + be.
// A_big[b, 4i+k] = {silu(x), x, x^2, x^3} bf16.
// B_big[o, 4i+k] = {W[o,i], C[o,i,1..3]} bf16; be[o] = bias[o] + sum_i C[o,i,0].
__global__ __launch_bounds__(256) void prep(const float* __restrict__ x,
                                            const float* __restrict__ W,
                                            const float* __restrict__ C,
                                            const float* __restrict__ bias,
                                            unsigned short* __restrict__ Ab,
                                            unsigned short* __restrict__ Bb,
                                            float* __restrict__ be) {
    if (blockIdx.x < 8192) {
        int idx = blockIdx.x * 256 + threadIdx.x;      // 8192*1024/4 threads
        float4 v = reinterpret_cast<const float4*>(x)[idx];
        float e0[4] = {v.x, v.y, v.z, v.w};
        unsigned short o[16];
#pragma unroll
        for (int j = 0; j < 4; ++j) {
            float xv = e0[j];
            float s  = xv / (1.0f + __expf(-xv));
            float x2 = xv * xv;
            o[4*j+0] = f2bf(s);
            o[4*j+1] = f2bf(xv);
            o[4*j+2] = f2bf(x2);
            o[4*j+3] = f2bf(x2 * xv);
        }
        uint4 d0 = make_uint4(pk(o[0],o[1]), pk(o[2],o[3]),   pk(o[4],o[5]),   pk(o[6],o[7]));
        uint4 d1 = make_uint4(pk(o[8],o[9]), pk(o[10],o[11]), pk(o[12],o[13]), pk(o[14],o[15]));
        uint4* dst = reinterpret_cast<uint4*>(Ab) + (size_t)idx * 2;
        dst[0] = d0;
        dst[1] = d1;
    } else {
        const int o = blockIdx.x - 8192, t = threadIdx.x;
        const int i0 = t * 4;
        const float4* c4 = reinterpret_cast<const float4*>(C + ((size_t)o * IN + i0) * 4);
        float4 w4 = *reinterpret_cast<const float4*>(W + (size_t)o * IN + i0);
        float wv[4] = {w4.x, w4.y, w4.z, w4.w};
        float s = 0.f;
        unsigned d[8];
#pragma unroll
        for (int j = 0; j < 4; ++j) {
            float4 c = c4[j];
            s += c.x;                                  // x^0 term -> bias
            d[2*j]   = pk(f2bf(wv[j]), f2bf(c.y));
            d[2*j+1] = pk(f2bf(c.z),   f2bf(c.w));
        }
        uint4* dst = reinterpret_cast<uint4*>(Bb + (size_t)o * KDIM + i0 * 4);
        dst[0] = make_uint4(d[0], d[1], d[2], d[3]);
        dst[1] = make_uint4(d[4], d[5], d[6], d[7]);
#pragma unroll
        for (int off = 32; off > 0; off >>= 1) s += __shfl_down(s, off, 64);
        __shared__ float red[4];
        if ((t & 63) == 0) red[t >> 6] = s;
        __syncthreads();
        if (t == 0) be[o] = bias[o] + red[0] + red[1] + red[2] + red[3];
    }
}

// C = A_big(8192x4096) * B_big(1024x4096)^T + be.
// 128x128 tile, BK=64, double-buffered LDS with ONE barrier per K-iter:
// loads for tile k+1 issue right after barrier k, so the vmcnt(0) drain at
// barrier k+1 waits on loads issued a full iteration ago (complete).
// XCD-aware remap; XOR-swizzled LDS (slot = kgroup ^ (row&7)), conflict-free.
__global__ __launch_bounds__(256, 2) void gemm_kan(
        const unsigned short* __restrict__ Ab,
        const unsigned short* __restrict__ Bb,
        const float* __restrict__ be,
        float* __restrict__ out) {
    __shared__ unsigned short sA[2][TM * BK];   // 2 x 16 KB
    __shared__ unsigned short sB[2][TN * BK];   // 2 x 16 KB

    const int t   = threadIdx.x;
    const int l   = blockIdx.x;              // 0..511
    const int bm  = (l & 7) * 8 + ((l >> 3) & 7);   // XCD (l&7) owns bm 8x..8x+7
    const int bn  = l >> 6;                  // 0..7
    const int lane = t & 63;
    const int wave = t >> 6;
    const int wr   = wave >> 1;              // 64-row half
    const int wc   = wave & 1;               // 64-col half
    const int l15  = lane & 15;
    const int quad = lane >> 4;

    // staging: thread t, load i in 0..3 -> LDS elems [i*2048 + t*8, +8)
    //   row = i*32 + (t>>3), slot = t&7, source kgroup g = slot ^ (row&7)
    const int rowT = t >> 3;                  // 0..31
    const int gT   = (t & 7) ^ (rowT & 7);
    const unsigned short* pa[4];
    const unsigned short* pb[4];
#pragma unroll
    for (int i = 0; i < 4; ++i) {
        pa[i] = Ab + (size_t)(bm * TM + i * 32 + rowT) * KDIM + gT * 8;
        pb[i] = Bb + (size_t)(bn * TN + i * 32 + rowT) * KDIM + gT * 8;
    }

    f32x4 acc[4][4];
    const f32x4 zero = {0.f, 0.f, 0.f, 0.f};
#pragma unroll
    for (int i = 0; i < 4; ++i)
#pragma unroll
        for (int j = 0; j < 4; ++j) acc[i][j] = zero;

    const int xr = l15 & 7;                   // row&7 for all fragment rows

    // prologue: stage tile 0 into buffer 0
#pragma unroll
    for (int i = 0; i < 4; ++i) {
        __builtin_amdgcn_global_load_lds((const GLOBAL_AS void*)pa[i],
                                         (LDS_AS void*)(sA[0] + i * 2048 + t * 8), 16, 0, 0);
        __builtin_amdgcn_global_load_lds((const GLOBAL_AS void*)pb[i],
                                         (LDS_AS void*)(sB[0] + i * 2048 + t * 8), 16, 0, 0);
    }

    for (int kt = 0; kt < NKT; ++kt) {
        __syncthreads();   // tile kt staged (vmcnt drain covers loads issued at kt-1)

        if (kt + 1 < NKT) {
            const int koff = (kt + 1) * BK;
            const int nb = (kt + 1) & 1;
#pragma unroll
            for (int i = 0; i < 4; ++i) {
                __builtin_amdgcn_global_load_lds((const GLOBAL_AS void*)(pa[i] + koff),
                                                 (LDS_AS void*)(sA[nb] + i * 2048 + t * 8), 16, 0, 0);
                __builtin_amdgcn_global_load_lds((const GLOBAL_AS void*)(pb[i] + koff),
                                                 (LDS_AS void*)(sB[nb] + i * 2048 + t * 8), 16, 0, 0);
            }
        }

        const unsigned short* a_base = sA[kt & 1];
        const unsigned short* b_base = sB[kt & 1];
#pragma unroll
        for (int kk = 0; kk < 2; ++kk) {
            const int cq = ((kk * 4 + quad) ^ xr) * 8;
            bf16x8 af[4], bv[4];
#pragma unroll
            for (int mi = 0; mi < 4; ++mi)
                af[mi] = *reinterpret_cast<const bf16x8*>(
                    a_base + (wr * 64 + mi * 16 + l15) * BK + cq);
#pragma unroll
            for (int ni = 0; ni < 4; ++ni)
                bv[ni] = *reinterpret_cast<const bf16x8*>(
                    b_base + (wc * 64 + ni * 16 + l15) * BK + cq);
#pragma unroll
            for (int mi = 0; mi < 4; ++mi)
#pragma unroll
                for (int ni = 0; ni < 4; ++ni)
                    acc[mi][ni] = __builtin_amdgcn_mfma_f32_16x16x32_bf16(
                        af[mi], bv[ni], acc[mi][ni], 0, 0, 0);
        }
    }

    // epilogue: C/D layout col = lane&15, row = quad*4 + reg
    float bev[4];
#pragma unroll
    for (int ni = 0; ni < 4; ++ni)
        bev[ni] = be[bn * TN + wc * 64 + ni * 16 + l15];

#pragma unroll
    for (int mi = 0; mi < 4; ++mi) {
        const int grow = bm * TM + wr * 64 + mi * 16 + quad * 4;
#pragma unroll
        for (int ni = 0; ni < 4; ++ni) {
            const int gcol = bn * TN + wc * 64 + ni * 16 + l15;
            float* po = out + (size_t)grow * OUT + gcol;
#pragma unroll
            for (int r = 0; r < 4; ++r)
                po[(size_t)r * OUT] = acc[mi][ni][r] + bev[ni];
        }
    }
}

extern "C" void kernel_launch(void* const* d_in, const int* in_sizes, int n_in,
                              void* d_out, int out_size, void* d_ws, size_t ws_size,
                              hipStream_t stream) {
    const float* x    = (const float*)d_in[0];   // [8192,1024]
    const float* W    = (const float*)d_in[1];   // [1024,1024]
    const float* C    = (const float*)d_in[2];   // [1024,1024,4]
    const float* bias = (const float*)d_in[3];   // [1024]
    float* out = (float*)d_out;

    unsigned short* Ab = (unsigned short*)d_ws;                    // 64 MB
    unsigned short* Bb = Ab + (size_t)BATCH * KDIM;                // 8 MB
    float*          be = (float*)(Bb + (size_t)OUT * KDIM);        // 4 KB

    prep<<<dim3(8192 + 1024), dim3(256), 0, stream>>>(x, W, C, bias, Ab, Bb, be);

    gemm_kan<<<dim3(512), dim3(256), 0, stream>>>(Ab, Bb, be, out);
}